// Round 5
// baseline (522.578 us; speedup 1.0000x reference)
//
#include <hip/hip_runtime.h>

#define N_NODES 50000
#define N_EDGES 1600000
#define D_FEAT 32
#define SCAN_THREADS 1024

// ws layout (int units):
//   cnt   [0, N)       per-dst edge count (histogram)
//   off   [N, 2N)      global exclusive offsets
//   rank  [2N, 2N+E)   rank of edge within its dst bin (coalesced write)
//   msg   [2N+E, ...)  bf16: E x 32 sorted messages (102.4 MB), 64 B per row
#define WS_CNT   0
#define WS_OFF   (N_NODES)
#define WS_RANK  (2 * N_NODES)
#define WS_MSG   (2 * N_NODES + N_EDGES)

static __device__ __forceinline__ unsigned short f2bf(float f) {
    unsigned u = __float_as_uint(f);
    unsigned r = (u + 0x7FFFu + ((u >> 16) & 1u)) >> 16;   // RNE
    return (unsigned short)r;
}
static __device__ __forceinline__ float bf2f(unsigned short h) {
    return __uint_as_float(((unsigned)h) << 16);
}

// rank[e] = old count of dst[e]; cnt accumulates histogram. rank write coalesced.
__global__ void hist_rank(const int* __restrict__ dst,
                          int* __restrict__ cnt,
                          int* __restrict__ rank) {
    int e = blockIdx.x * blockDim.x + threadIdx.x;
    if (e < N_EDGES) rank[e] = atomicAdd(&cnt[dst[e]], 1);
}

// Single-workgroup exclusive scan of 50K counts: per-thread serial sums ->
// LDS Hillis-Steele over 1024 partials -> per-thread serial write of offsets.
__global__ void scan_all(const int* __restrict__ cnt, int* __restrict__ off) {
    __shared__ int part[SCAN_THREADS];
    const int PER = (N_NODES + SCAN_THREADS - 1) / SCAN_THREADS;  // 49
    int t = threadIdx.x;
    int base = t * PER;
    int s = 0;
    for (int i = 0; i < PER; ++i) {
        int idx = base + i;
        if (idx < N_NODES) s += cnt[idx];
    }
    part[t] = s;
    __syncthreads();
    for (int o = 1; o < SCAN_THREADS; o <<= 1) {
        int v = (t >= o) ? part[t - o] : 0;
        __syncthreads();
        part[t] += v;
        __syncthreads();
    }
    int run = (t > 0) ? part[t - 1] : 0;
    for (int i = 0; i < PER; ++i) {
        int idx = base + i;
        if (idx < N_NODES) { off[idx] = run; run += cnt[idx]; }
    }
}

// 8 lanes per edge: m = relu(nf[src] + ef) -> bf16, write the full 64 B
// message row to its dst-sorted slot (one sector, no write amplification).
__global__ void build_msg_bf16(const float* __restrict__ node_feat,
                               const float* __restrict__ edge_feat,
                               const int* __restrict__ src,
                               const int* __restrict__ dst,
                               const int* __restrict__ off,
                               const int* __restrict__ rank,
                               unsigned int* __restrict__ msg) {
    int t = blockIdx.x * blockDim.x + threadIdx.x;
    int e = t >> 3;
    int g = t & 7;
    if (e >= N_EDGES) return;

    int d = dst[e];
    int pos = off[d] + rank[e];
    int s = src[e];

    float4 ef = ((const float4*)edge_feat)[(size_t)e * 8 + g];
    float4 nf = ((const float4*)node_feat)[s * 8 + g];
    float m0 = fmaxf(nf.x + ef.x, 0.f);
    float m1 = fmaxf(nf.y + ef.y, 0.f);
    float m2 = fmaxf(nf.z + ef.z, 0.f);
    float m3 = fmaxf(nf.w + ef.w, 0.f);

    uint2 packed;
    packed.x = (unsigned)f2bf(m0) | ((unsigned)f2bf(m1) << 16);
    packed.y = (unsigned)f2bf(m2) | ((unsigned)f2bf(m3) << 16);
    ((uint2*)msg)[(size_t)pos * 8 + g] = packed;
}

// per (node, 4-feat group): fp32-accumulate the node's contiguous bf16
// message rows + fused (1+eps)*h residual.
__global__ void reduce_msgs(const float* __restrict__ node_feat,
                            const float* __restrict__ eps,
                            const int* __restrict__ off,
                            const int* __restrict__ cnt,
                            const unsigned int* __restrict__ msg,
                            float* __restrict__ out) {
    int t = blockIdx.x * blockDim.x + threadIdx.x;
    int n = t >> 3;
    int g = t & 7;
    if (n >= N_NODES) return;

    int start = off[n];
    int c = cnt[n];

    float4 acc = make_float4(0.f, 0.f, 0.f, 0.f);
    for (int i = 0; i < c; ++i) {
        uint2 m = ((const uint2*)msg)[(size_t)(start + i) * 8 + g];
        acc.x += bf2f((unsigned short)(m.x & 0xFFFF));
        acc.y += bf2f((unsigned short)(m.x >> 16));
        acc.z += bf2f((unsigned short)(m.y & 0xFFFF));
        acc.w += bf2f((unsigned short)(m.y >> 16));
    }

    float scale = 1.0f + eps[0];
    float4 h = ((const float4*)node_feat)[n * 8 + g];
    float4 o;
    o.x = scale * h.x + acc.x;
    o.y = scale * h.y + acc.y;
    o.z = scale * h.z + acc.z;
    o.w = scale * h.w + acc.w;
    ((float4*)out)[n * 8 + g] = o;
}

// -------- fallback path (tiny ws): direct fp32 atomics --------

__global__ void fb_init_out(const float* __restrict__ node_feat,
                            const float* __restrict__ eps,
                            float* __restrict__ out) {
    int i = blockIdx.x * blockDim.x + threadIdx.x;
    const int n4 = N_NODES * D_FEAT / 4;
    float scale = 1.0f + eps[0];
    if (i < n4) {
        float4 v = ((const float4*)node_feat)[i];
        v.x *= scale; v.y *= scale; v.z *= scale; v.w *= scale;
        ((float4*)out)[i] = v;
    }
}

__global__ void fb_scatter(const float* __restrict__ node_feat,
                           const float* __restrict__ edge_feat,
                           const int* __restrict__ src,
                           const int* __restrict__ dst,
                           float* __restrict__ out) {
    int t = blockIdx.x * blockDim.x + threadIdx.x;
    int e = t >> 3;
    int g = t & 7;
    if (e >= N_EDGES) return;
    int s = src[e];
    int d = dst[e];
    float4 nf = ((const float4*)node_feat)[s * 8 + g];
    float4 ef = ((const float4*)edge_feat)[(size_t)e * 8 + g];
    float* op = out + (size_t)d * D_FEAT + g * 4;
    unsafeAtomicAdd(op + 0, fmaxf(nf.x + ef.x, 0.f));
    unsafeAtomicAdd(op + 1, fmaxf(nf.y + ef.y, 0.f));
    unsafeAtomicAdd(op + 2, fmaxf(nf.z + ef.z, 0.f));
    unsafeAtomicAdd(op + 3, fmaxf(nf.w + ef.w, 0.f));
}

extern "C" void kernel_launch(void* const* d_in, const int* in_sizes, int n_in,
                              void* d_out, int out_size, void* d_ws, size_t ws_size,
                              hipStream_t stream) {
    const float* node_feat = (const float*)d_in[0];
    const float* edge_feat = (const float*)d_in[1];
    const float* eps       = (const float*)d_in[2];
    const int*   src       = (const int*)d_in[3];
    const int*   dst       = (const int*)d_in[4];
    float* out = (float*)d_out;

    const int B = 256;
    // need: ints through WS_MSG, then E rows x 64 B of bf16 messages
    const size_t need = (size_t)WS_MSG * sizeof(int) + (size_t)N_EDGES * 64;

    if (ws_size < need) {
        int n4 = N_NODES * D_FEAT / 4;
        fb_init_out<<<(n4 + B - 1) / B, B, 0, stream>>>(node_feat, eps, out);
        long long total = (long long)N_EDGES * 8;
        fb_scatter<<<(int)((total + B - 1) / B), B, 0, stream>>>(
            node_feat, edge_feat, src, dst, out);
        return;
    }

    int* ws = (int*)d_ws;
    int*          cnt  = ws + WS_CNT;
    int*          off  = ws + WS_OFF;
    int*          rank = ws + WS_RANK;
    unsigned int* msg  = (unsigned int*)(ws + WS_MSG);

    hipMemsetAsync(cnt, 0, N_NODES * sizeof(int), stream);

    hist_rank<<<(N_EDGES + B - 1) / B, B, 0, stream>>>(dst, cnt, rank);
    scan_all<<<1, SCAN_THREADS, 0, stream>>>(cnt, off);

    long long etotal = (long long)N_EDGES * 8;
    build_msg_bf16<<<(int)((etotal + B - 1) / B), B, 0, stream>>>(
        node_feat, edge_feat, src, dst, off, rank, msg);

    long long ntotal = (long long)N_NODES * 8;
    reduce_msgs<<<(int)((ntotal + B - 1) / B), B, 0, stream>>>(
        node_feat, eps, off, cnt, msg, out);
}

// Round 6
// 513.079 us; speedup vs baseline: 1.0185x; 1.0185x over previous
//
#include <hip/hip_runtime.h>

#define N_NODES 50000
#define N_EDGES 1600000
#define D_FEAT 32
#define SCAN_THREADS 1024

// ws layout (int units):
//   cnt   [0, N)        per-dst edge count (histogram)
//   off   [N, 2N)       global exclusive offsets
//   rank  [2N, 2N+E)    rank of edge within its dst bin (coalesced write)
//   pairs [2N+E, ...)   int2 (edge_id, src) at dst-sorted positions (12.8 MB)
#define WS_CNT   0
#define WS_OFF   (N_NODES)
#define WS_RANK  (2 * N_NODES)
#define WS_PAIRS (2 * N_NODES + N_EDGES)

// rank[e] = old count of dst[e]; cnt accumulates histogram. rank write coalesced.
__global__ void hist_rank(const int* __restrict__ dst,
                          int* __restrict__ cnt,
                          int* __restrict__ rank) {
    int e = blockIdx.x * blockDim.x + threadIdx.x;
    if (e < N_EDGES) rank[e] = atomicAdd(&cnt[dst[e]], 1);
}

// Single-workgroup exclusive scan of 50K counts.
__global__ void scan_all(const int* __restrict__ cnt, int* __restrict__ off) {
    __shared__ int part[SCAN_THREADS];
    const int PER = (N_NODES + SCAN_THREADS - 1) / SCAN_THREADS;  // 49
    int t = threadIdx.x;
    int base = t * PER;
    int s = 0;
    for (int i = 0; i < PER; ++i) {
        int idx = base + i;
        if (idx < N_NODES) s += cnt[idx];
    }
    part[t] = s;
    __syncthreads();
    for (int o = 1; o < SCAN_THREADS; o <<= 1) {
        int v = (t >= o) ? part[t - o] : 0;
        __syncthreads();
        part[t] += v;
        __syncthreads();
    }
    int run = (t > 0) ? part[t - 1] : 0;
    for (int i = 0; i < PER; ++i) {
        int idx = base + i;
        if (idx < N_NODES) { off[idx] = run; run += cnt[idx]; }
    }
}

// One thread per edge: place (edge_id, src) at its dst-sorted slot.
// 8 B random write -> ~64 B sector traffic per edge (the only amplified pass).
__global__ void scatter_pairs(const int* __restrict__ src,
                              const int* __restrict__ dst,
                              const int* __restrict__ off,
                              const int* __restrict__ rank,
                              int2* __restrict__ pairs) {
    int e = blockIdx.x * blockDim.x + threadIdx.x;
    if (e >= N_EDGES) return;
    int p = off[dst[e]] + rank[e];
    pairs[p] = make_int2(e, src[e]);
}

// One wave per node: lane = (sub, g), sub in [0,8) slices the edge list,
// g in [0,8) owns float4 feature group. Gather edge_feat rows directly
// (read once, full 128 B rows), node_feat is L2/L3-resident. Messages are
// never materialized. __shfl_xor tree folds the 8 subs; sub 0 writes out.
__global__ void reduce_gather(const float* __restrict__ node_feat,
                              const float* __restrict__ edge_feat,
                              const float* __restrict__ eps,
                              const int* __restrict__ off,
                              const int* __restrict__ cnt,
                              const int2* __restrict__ pairs,
                              float* __restrict__ out) {
    int wave = (blockIdx.x * blockDim.x + threadIdx.x) >> 6;
    int lane = threadIdx.x & 63;
    if (wave >= N_NODES) return;
    int n = wave;
    int g = lane & 7;
    int sub = lane >> 3;

    int start = off[n];
    int c = cnt[n];

    float4 acc = make_float4(0.f, 0.f, 0.f, 0.f);
    for (int i = sub; i < c; i += 8) {
        int2 pr = pairs[start + i];
        float4 ef = ((const float4*)edge_feat)[(size_t)pr.x * 8 + g];
        float4 nf = ((const float4*)node_feat)[pr.y * 8 + g];
        acc.x += fmaxf(nf.x + ef.x, 0.f);
        acc.y += fmaxf(nf.y + ef.y, 0.f);
        acc.z += fmaxf(nf.z + ef.z, 0.f);
        acc.w += fmaxf(nf.w + ef.w, 0.f);
    }

    // fold subs: lanes differing in bits 3..5 share the same g
    for (int m = 8; m < 64; m <<= 1) {
        acc.x += __shfl_xor(acc.x, m);
        acc.y += __shfl_xor(acc.y, m);
        acc.z += __shfl_xor(acc.z, m);
        acc.w += __shfl_xor(acc.w, m);
    }

    if (sub == 0) {
        float scale = 1.0f + eps[0];
        float4 h = ((const float4*)node_feat)[n * 8 + g];
        float4 o;
        o.x = scale * h.x + acc.x;
        o.y = scale * h.y + acc.y;
        o.z = scale * h.z + acc.z;
        o.w = scale * h.w + acc.w;
        ((float4*)out)[n * 8 + g] = o;
    }
}

// -------- fallback path (tiny ws): direct fp32 atomics --------

__global__ void fb_init_out(const float* __restrict__ node_feat,
                            const float* __restrict__ eps,
                            float* __restrict__ out) {
    int i = blockIdx.x * blockDim.x + threadIdx.x;
    const int n4 = N_NODES * D_FEAT / 4;
    float scale = 1.0f + eps[0];
    if (i < n4) {
        float4 v = ((const float4*)node_feat)[i];
        v.x *= scale; v.y *= scale; v.z *= scale; v.w *= scale;
        ((float4*)out)[i] = v;
    }
}

__global__ void fb_scatter(const float* __restrict__ node_feat,
                           const float* __restrict__ edge_feat,
                           const int* __restrict__ src,
                           const int* __restrict__ dst,
                           float* __restrict__ out) {
    int t = blockIdx.x * blockDim.x + threadIdx.x;
    int e = t >> 3;
    int g = t & 7;
    if (e >= N_EDGES) return;
    int s = src[e];
    int d = dst[e];
    float4 nf = ((const float4*)node_feat)[s * 8 + g];
    float4 ef = ((const float4*)edge_feat)[(size_t)e * 8 + g];
    float* op = out + (size_t)d * D_FEAT + g * 4;
    unsafeAtomicAdd(op + 0, fmaxf(nf.x + ef.x, 0.f));
    unsafeAtomicAdd(op + 1, fmaxf(nf.y + ef.y, 0.f));
    unsafeAtomicAdd(op + 2, fmaxf(nf.z + ef.z, 0.f));
    unsafeAtomicAdd(op + 3, fmaxf(nf.w + ef.w, 0.f));
}

extern "C" void kernel_launch(void* const* d_in, const int* in_sizes, int n_in,
                              void* d_out, int out_size, void* d_ws, size_t ws_size,
                              hipStream_t stream) {
    const float* node_feat = (const float*)d_in[0];
    const float* edge_feat = (const float*)d_in[1];
    const float* eps       = (const float*)d_in[2];
    const int*   src       = (const int*)d_in[3];
    const int*   dst       = (const int*)d_in[4];
    float* out = (float*)d_out;

    const int B = 256;
    const size_t need = (size_t)WS_PAIRS * sizeof(int) + (size_t)N_EDGES * sizeof(int2);

    if (ws_size < need) {
        int n4 = N_NODES * D_FEAT / 4;
        fb_init_out<<<(n4 + B - 1) / B, B, 0, stream>>>(node_feat, eps, out);
        long long total = (long long)N_EDGES * 8;
        fb_scatter<<<(int)((total + B - 1) / B), B, 0, stream>>>(
            node_feat, edge_feat, src, dst, out);
        return;
    }

    int*  ws    = (int*)d_ws;
    int*  cnt   = ws + WS_CNT;
    int*  off   = ws + WS_OFF;
    int*  rank  = ws + WS_RANK;
    int2* pairs = (int2*)(ws + WS_PAIRS);

    hipMemsetAsync(cnt, 0, N_NODES * sizeof(int), stream);

    hist_rank<<<(N_EDGES + B - 1) / B, B, 0, stream>>>(dst, cnt, rank);
    scan_all<<<1, SCAN_THREADS, 0, stream>>>(cnt, off);
    scatter_pairs<<<(N_EDGES + B - 1) / B, B, 0, stream>>>(src, dst, off, rank, pairs);

    // one wave per node
    long long rthreads = (long long)N_NODES * 64;
    reduce_gather<<<(int)((rthreads + B - 1) / B), B, 0, stream>>>(
        node_feat, edge_feat, eps, off, cnt, pairs, out);
}